// Round 2
// baseline (7198.193 us; speedup 1.0000x reference)
//
#include <hip/hip_runtime.h>
#include <hip/hip_bf16.h>
#include <cstdint>

// ---------------------------------------------------------------------------
// Problem constants
// ---------------------------------------------------------------------------
#define BATCH   16
#define CIN0    80
#define T_IN    2048
#define HID1    512
#define HID2    1024
#define T1      1024      // after conv1 (stride 2)
#define T2      512       // after conv2 (stride 2)
#define CODE_DIM 512
#define N_TOK   8192
#define N_RES   3
#define N_ROWS  (BATCH * T2)   // 8192 latent vectors

// ---------------------------------------------------------------------------
// Generic conv1d:  out[b,o,t] = sum_{i,k} w[o,i,k] * in[b,i,t*S + k - PAD]
// Tile: BO=128 outputs x BT=128 time steps, 256 threads, 8x8 per-thread tile.
// Weights staged to LDS as [i][k][o] (o contiguous -> b128 reads, broadcast
// across the 16 t-group lanes). Inputs staged [i][t] (b128 reads, broadcast
// across the 4 o-group lanes of a wave).
// ---------------------------------------------------------------------------
template<int K, int S, int PAD, bool RELU, bool ADD>
__global__ __launch_bounds__(256, 2)
void conv1d_kernel(const float* __restrict__ in,
                   const float* __restrict__ w,
                   const float* __restrict__ bias,
                   const float* __restrict__ addsrc,
                   float* __restrict__ out,
                   int Cin, int Cout, int Tin, int Tout)
{
    constexpr int BO = 128, BT = 128, BI = 16;
    constexpr int IN_W = (BT - 1) * S + K;          // input span of the tile
    constexpr int LDW  = (IN_W + 3) & ~3;           // 16B-aligned row stride
    constexpr int NIN  = ((7 * S + K) + 3) & ~3;    // per-thread input regs
    static_assert((BI * K) % 4 == 0, "weight chunking");

    __shared__ float s_in[BI][LDW];
    __shared__ float s_w[BI][K][BO];

    const int tid = threadIdx.x;
    const int tg  = tid & 15;    // t-group: 16 groups x 8 t
    const int og  = tid >> 4;    // o-group: 16 groups x 8 o
    const int t0  = blockIdx.x * BT;
    const int o0  = blockIdx.y * BO;
    const int b   = blockIdx.z;
    const int tin0 = t0 * S - PAD;

    float acc[8][8];
#pragma unroll
    for (int i = 0; i < 8; ++i)
#pragma unroll
        for (int j = 0; j < 8; ++j) acc[i][j] = 0.f;

    const int ldr = tid >> 4;   // staging row (0..15)
    const int ldx = tid & 15;   // staging lane within row

    for (int i0 = 0; i0 < Cin; i0 += BI) {
        __syncthreads();
        // ---- stage input tile [BI][IN_W] (zero-padded at edges) ----
        {
            const float* src = in + ((size_t)b * Cin + (i0 + ldr)) * (size_t)Tin;
            for (int x = ldx; x < IN_W; x += 16) {
                const int t = tin0 + x;
                s_in[ldr][x] = (t >= 0 && t < Tin) ? src[t] : 0.f;
            }
        }
        // ---- stage weights [BI][K][BO] from w[o][i][k] (float4 chunks) ----
        {
            constexpr int CH = BI * K / 4;          // float4 chunks per o
            for (int task = tid; task < BO * CH; task += 256) {
                const int o = task / CH, c = task % CH;
                const float4 v = *(const float4*)(w + ((size_t)(o0 + o) * Cin + i0) * K + c * 4);
                const float vv[4] = {v.x, v.y, v.z, v.w};
#pragma unroll
                for (int u = 0; u < 4; ++u) {
                    const int e = c * 4 + u;
                    s_w[e / K][e % K][o] = vv[u];
                }
            }
        }
        __syncthreads();
        // ---- compute ----
#pragma unroll 2
        for (int i = 0; i < BI; ++i) {
            float xin[NIN];
#pragma unroll
            for (int q = 0; q < NIN / 4; ++q)
                *(float4*)&xin[q * 4] = *(const float4*)&s_in[i][tg * 8 * S + q * 4];
            float wv[K][8];
#pragma unroll
            for (int k = 0; k < K; ++k) {
                *(float4*)&wv[k][0] = *(const float4*)&s_w[i][k][og * 8];
                *(float4*)&wv[k][4] = *(const float4*)&s_w[i][k][og * 8 + 4];
            }
#pragma unroll
            for (int oo = 0; oo < 8; ++oo)
#pragma unroll
                for (int tt = 0; tt < 8; ++tt)
#pragma unroll
                    for (int k = 0; k < K; ++k)
                        acc[oo][tt] += wv[k][oo] * xin[tt * S + k];
        }
    }

    // ---- epilogue: bias (+residual) (+relu), float4 stores ----
#pragma unroll
    for (int oo = 0; oo < 8; ++oo) {
        const float bv = bias[o0 + og * 8 + oo];
        const size_t base = ((size_t)b * Cout + (o0 + og * 8 + oo)) * (size_t)Tout + t0 + tg * 8;
        float r[8];
#pragma unroll
        for (int tt = 0; tt < 8; ++tt) {
            float v = acc[oo][tt] + bv;
            if constexpr (ADD) v += addsrc[base + tt];
            if constexpr (RELU) v = fmaxf(v, 0.f);
            r[tt] = v;
        }
        *(float4*)(out + base)     = make_float4(r[0], r[1], r[2], r[3]);
        *(float4*)(out + base + 4) = make_float4(r[4], r[5], r[6], r[7]);
    }
}

// ---------------------------------------------------------------------------
// Codebook squared norms: cnorm[j] = sum_d cb[d][j]^2
// ---------------------------------------------------------------------------
__global__ void cnorm_kernel(const float* __restrict__ cb, float* __restrict__ cnorm)
{
    const int j = blockIdx.x * 256 + threadIdx.x;
    float s = 0.f;
#pragma unroll 8
    for (int d = 0; d < CODE_DIM; ++d) {
        const float v = cb[(size_t)d * N_TOK + j];
        s += v * v;
    }
    cnorm[j] = s;
}

// ---------------------------------------------------------------------------
// VQ partial argmax of (2*f.c - |c|^2) over a slice of 1024 codes.
// Block: 128 rows x 1024 codes (in 128-code tiles). 8 slices x 64 row tiles.
// Rows are (b, t) with features along lat's channel dim (f[row][d]=lat[b][d][t]).
// ---------------------------------------------------------------------------
__global__ __launch_bounds__(256, 2)
void vq_partial(const float* __restrict__ lat, const float* __restrict__ cb,
                const float* __restrict__ cnorm,
                float* __restrict__ pval, int* __restrict__ pidx)
{
    constexpr int BR = 128, BJ = 128, BD = 16, JSPAN = 1024;
    __shared__ float s_f[BD][BR];
    __shared__ float s_c[BD][BJ];
    __shared__ float m_v[BR][16];
    __shared__ int   m_i[BR][16];

    const int tid = threadIdx.x;
    const int rg = tid & 15;      // 16 row-groups x 8 rows
    const int jg = tid >> 4;      // 16 code-groups x 8 codes
    const int row0 = blockIdx.x * BR;
    const int b  = row0 >> 9;     // row = b*512 + t
    const int t0 = row0 & 511;
    const int jbase = blockIdx.y * JSPAN;

    const int ldr = tid >> 4, ldx = tid & 15;

    float bestv[8];
    int   besti[8];
#pragma unroll
    for (int r = 0; r < 8; ++r) { bestv[r] = -3.4e38f; besti[r] = 0; }

    for (int jt = 0; jt < JSPAN; jt += BJ) {
        const int j0 = jbase + jt;
        float s[8][8];
#pragma unroll
        for (int r = 0; r < 8; ++r)
#pragma unroll
            for (int j = 0; j < 8; ++j) s[r][j] = 0.f;

        for (int d0 = 0; d0 < CODE_DIM; d0 += BD) {
            __syncthreads();
            for (int x = ldx; x < BR; x += 16)
                s_f[ldr][x] = lat[((size_t)b * CODE_DIM + d0 + ldr) * (size_t)T2 + t0 + x];
            for (int x = ldx; x < BJ; x += 16)
                s_c[ldr][x] = cb[(size_t)(d0 + ldr) * N_TOK + j0 + x];
            __syncthreads();
#pragma unroll
            for (int d = 0; d < BD; ++d) {
                float fv[8], cv[8];
                *(float4*)&fv[0] = *(const float4*)&s_f[d][rg * 8];
                *(float4*)&fv[4] = *(const float4*)&s_f[d][rg * 8 + 4];
                *(float4*)&cv[0] = *(const float4*)&s_c[d][jg * 8];
                *(float4*)&cv[4] = *(const float4*)&s_c[d][jg * 8 + 4];
#pragma unroll
                for (int r = 0; r < 8; ++r)
#pragma unroll
                    for (int j = 0; j < 8; ++j)
                        s[r][j] += fv[r] * cv[j];
            }
        }
        // epilogue: running argmax (ascending j => strict > keeps first min)
#pragma unroll
        for (int j = 0; j < 8; ++j) {
            const int jj = j0 + jg * 8 + j;
            const float cn = cnorm[jj];
#pragma unroll
            for (int r = 0; r < 8; ++r) {
                const float v = 2.f * s[r][j] - cn;
                if (v > bestv[r]) { bestv[r] = v; besti[r] = jj; }
            }
        }
    }

    // merge across the 16 code-groups
#pragma unroll
    for (int r = 0; r < 8; ++r) { m_v[rg * 8 + r][jg] = bestv[r]; m_i[rg * 8 + r][jg] = besti[r]; }
    __syncthreads();
    if (tid < BR) {
        float bv = m_v[tid][0]; int bi = m_i[tid][0];
#pragma unroll
        for (int g = 1; g < 16; ++g) {
            const float v = m_v[tid][g]; const int i2 = m_i[tid][g];
            if (v > bv || (v == bv && i2 < bi)) { bv = v; bi = i2; }
        }
        pval[(size_t)blockIdx.y * N_ROWS + row0 + tid] = bv;
        pidx[(size_t)blockIdx.y * N_ROWS + row0 + tid] = bi;
    }
}

// ---------------------------------------------------------------------------
// Final merge over the 8 code slices; output is int32 codes (the harness
// reads d_out as np.int32 for this reference -- write raw ints, NOT floats).
// ---------------------------------------------------------------------------
__global__ void vq_final(const float* __restrict__ pval, const int* __restrict__ pidx,
                         int* __restrict__ out)
{
    const int row = blockIdx.x * 256 + threadIdx.x;
    float bv = pval[row]; int bi = pidx[row];
#pragma unroll
    for (int q = 1; q < 8; ++q) {
        const float v = pval[(size_t)q * N_ROWS + row];
        const int i2  = pidx[(size_t)q * N_ROWS + row];
        if (v > bv || (v == bv && i2 < bi)) { bv = v; bi = i2; }
    }
    out[row] = bi;
}

// ---------------------------------------------------------------------------
// Launch
// ---------------------------------------------------------------------------
extern "C" void kernel_launch(void* const* d_in, const int* in_sizes, int n_in,
                              void* d_out, int out_size, void* d_ws, size_t ws_size,
                              hipStream_t stream)
{
    const float* x   = (const float*)d_in[0];
    const float* w1  = (const float*)d_in[1];
    const float* b1  = (const float*)d_in[2];
    const float* w2  = (const float*)d_in[3];
    const float* b2  = (const float*)d_in[4];
    const float* rwa = (const float*)d_in[5];
    const float* rba = (const float*)d_in[6];
    const float* rwb = (const float*)d_in[7];
    const float* rbb = (const float*)d_in[8];
    const float* rwc = (const float*)d_in[9];
    const float* rbc = (const float*)d_in[10];
    const float* wf  = (const float*)d_in[11];
    const float* bf  = (const float*)d_in[12];
    const float* cb  = (const float*)d_in[13];

    float* ws = (float*)d_ws;
    // workspace layout (floats):
    //   B0 [8.39M] : h1 -> r1 -> lat
    //   B1 [8.39M] : h2 (persistent across resblocks)
    //   B2 [8.39M] : r2
    //   CN [8192], PV [8*8192], PI [8*8192]
    float* B0 = ws;
    float* B1 = ws + 8388608;
    float* B2 = ws + 16777216;
    float* CN = ws + 25165824;
    float* PV = ws + 25174016;
    int*   PI = (int*)(ws + 25239552);

    float* h1  = B0;
    float* h2  = B1;
    float* r1  = B0;
    float* r2  = B2;
    float* lat = B0;

    // conv1: [16,80,2048] -> relu -> [16,512,1024]
    conv1d_kernel<3, 2, 1, true, false><<<dim3(T1 / 128, HID1 / 128, BATCH), 256, 0, stream>>>(
        x, w1, b1, nullptr, h1, CIN0, HID1, T_IN, T1);
    // conv2: -> relu -> [16,1024,512]
    conv1d_kernel<3, 2, 1, true, false><<<dim3(T2 / 128, HID2 / 128, BATCH), 256, 0, stream>>>(
        h1, w2, b2, nullptr, h2, HID1, HID2, T1, T2);
    // 3 resblocks
    for (int i = 0; i < N_RES; ++i) {
        const float* wa = rwa + (size_t)i * HID2 * HID2 * 3;
        const float* ba = rba + (size_t)i * HID2;
        const float* wb = rwb + (size_t)i * HID2 * HID2 * 3;
        const float* bb = rbb + (size_t)i * HID2;
        const float* wc = rwc + (size_t)i * HID2 * HID2;
        const float* bc = rbc + (size_t)i * HID2;
        conv1d_kernel<3, 1, 1, true, false><<<dim3(T2 / 128, HID2 / 128, BATCH), 256, 0, stream>>>(
            h2, wa, ba, nullptr, r1, HID2, HID2, T2, T2);
        conv1d_kernel<3, 1, 1, true, false><<<dim3(T2 / 128, HID2 / 128, BATCH), 256, 0, stream>>>(
            r1, wb, bb, nullptr, r2, HID2, HID2, T2, T2);
        conv1d_kernel<1, 1, 0, false, true><<<dim3(T2 / 128, HID2 / 128, BATCH), 256, 0, stream>>>(
            r2, wc, bc, h2, h2, HID2, HID2, T2, T2);
    }
    // final 1x1: [16,1024,512] -> [16,512,512]
    conv1d_kernel<1, 1, 0, false, false><<<dim3(T2 / 128, CODE_DIM / 128, BATCH), 256, 0, stream>>>(
        h2, wf, bf, nullptr, lat, HID2, CODE_DIM, T2, T2);

    // VQ argmin
    cnorm_kernel<<<N_TOK / 256, 256, 0, stream>>>(cb, CN);
    vq_partial<<<dim3(N_ROWS / 128, 8), 256, 0, stream>>>(lat, cb, CN, PV, PI);
    vq_final<<<N_ROWS / 256, 256, 0, stream>>>(PV, PI, (int*)d_out);
}

// Round 3
// 4406.818 us; speedup vs baseline: 1.6334x; 1.6334x over previous
//
#include <hip/hip_runtime.h>
#include <cstdint>

// ---------------------------------------------------------------------------
// Problem constants
// ---------------------------------------------------------------------------
#define BATCH   16
#define T_IN    2048
#define HID1    512
#define HID2    1024
#define T1      1024
#define T2      512
#define CODE_DIM 512
#define N_TOK   8192
#define N_RES   3
#define N_ROWS  (BATCH * T2)      // 8192 latent rows

typedef short bf16x8 __attribute__((ext_vector_type(8)));   // 8 bf16 = 4 VGPR
typedef float f32x4  __attribute__((ext_vector_type(4)));   // MFMA C/D

union B128 { int4 i; bf16x8 b; };

// bf16x2 split: packed u32 = hi_bits | (lo_bits << 16); v ~= bf16(hi) + bf16(lo)
__device__ __forceinline__ unsigned splitpack(float v) {
    unsigned r  = __float_as_uint(v);
    unsigned hi = (r + 0x7FFFu + ((r >> 16) & 1u)) >> 16;       // RNE bf16
    float    res = v - __uint_as_float(hi << 16);               // exact
    unsigned rl = __float_as_uint(res);
    unsigned lo = (rl + 0x7FFFu + ((rl >> 16) & 1u)) >> 16;     // RNE bf16
    return hi | (lo << 16);
}
__device__ __forceinline__ float unsplit(unsigned p) {
    return __uint_as_float((p & 0xFFFFu) << 16) + __uint_as_float(p & 0xFFFF0000u);
}
__device__ __forceinline__ int swz(int row) { return (row ^ (row >> 2)) & 3; }

// Stage one row of 32 packed elems into hi/lo bf16 LDS planes (swizzled slots).
__device__ __forceinline__ void stage_row_packed(const int4* __restrict__ src, bool valid,
                                                 int4 (*sH)[4], int4 (*sL)[4], int row) {
    const int s = swz(row);
#pragma unroll
    for (int j = 0; j < 4; ++j) {
        int4 a = {0,0,0,0}, b = {0,0,0,0};
        if (valid) { a = src[j*2]; b = src[j*2+1]; }
        int4 h, l;
        h.x = (a.x & 0xFFFF) | (a.y << 16);  l.x = (int)(((unsigned)a.x >> 16) | ((unsigned)a.y & 0xFFFF0000u));
        h.y = (a.z & 0xFFFF) | (a.w << 16);  l.y = (int)(((unsigned)a.z >> 16) | ((unsigned)a.w & 0xFFFF0000u));
        h.z = (b.x & 0xFFFF) | (b.y << 16);  l.z = (int)(((unsigned)b.x >> 16) | ((unsigned)b.y & 0xFFFF0000u));
        h.w = (b.z & 0xFFFF) | (b.w << 16);  l.w = (int)(((unsigned)b.z >> 16) | ((unsigned)b.w & 0xFFFF0000u));
        sH[row][j ^ s] = h;  sL[row][j ^ s] = l;
    }
}

// ---------------------------------------------------------------------------
// MFMA implicit-GEMM conv1d.
//   out[b,t,o] = relu( sum_{c,k} X[b, t*S + k - PAD, c] * w[o,c,k] + bias[o] (+ add) )
// M = b*Tout + t rows, N = Cout. A = X (packed bf16x2), B = W (split in-kernel
// from raw fp32). 256 thr = 4 waves (2x2), wave tile WM x 64, block 2*WM x 128.
// bf16x2: acc += Ah*Bh + Ah*Bl + Al*Bh  (3 MFMA per logical MFMA).
// ---------------------------------------------------------------------------
template<int TAPS, int S, int WM, bool XRAW, bool RELU, bool ADD>
__global__ __launch_bounds__(256, 2)
void conv_mfma(const void* __restrict__ xsrc, const float* __restrict__ wraw,
               const float* __restrict__ bias, const unsigned* __restrict__ addsrc,
               unsigned* __restrict__ out,
               int CinPad, int CinReal, int Cout, int Tin, int Tout)
{
    constexpr int BM = WM * 2, BN = 128;
    constexpr int PAD  = (TAPS == 3) ? 1 : 0;
    constexpr int SPAN = BM * S + TAPS - S;
    constexpr int MF   = WM / 16;

    __shared__ int4 sXh[SPAN][4], sXl[SPAN][4];
    __shared__ int4 sWh[BN][4],  sWl[BN][4];

    const int tid  = threadIdx.x;
    const int lane = tid & 63, wid = tid >> 6;
    const int wm = wid >> 1, wn = wid & 1;
    const int l15 = lane & 15, l4 = lane >> 4;

    const int R0 = blockIdx.x * BM;           // global row base (b*Tout + t)
    const int o0 = blockIdx.y * BN;
    const int b  = R0 / Tout, t0 = R0 % Tout; // BM divides Tout -> one b per block
    const int tbase = t0 * S - PAD;

    f32x4 acc[MF][4] = {};

    for (int c0 = 0; c0 < CinPad; c0 += 32) {
        for (int tap = 0; tap < TAPS; ++tap) {
            __syncthreads();
            if (tap == 0) {
                if constexpr (XRAW) {
                    // x: fp32 [B][CinReal][Tin] -> transpose+split into LDS
                    const float* xf = (const float*)xsrc;
                    const int ci = tid & 31, seg = tid >> 5;
                    const int c = c0 + ci;
                    const float* xp = xf + ((size_t)b * CinReal + c) * (size_t)Tin;
                    unsigned short* pH = (unsigned short*)&sXh[0][0];
                    unsigned short* pL = (unsigned short*)&sXl[0][0];
                    const int per = (SPAN + 7) / 8;
                    const int rs = seg * per, re = (rs + per < SPAN) ? rs + per : SPAN;
                    for (int r = rs; r < re; ++r) {
                        const int t = tbase + r;
                        float v = (c < CinReal && t >= 0 && t < Tin) ? xp[t] : 0.f;
                        unsigned p = splitpack(v);
                        const int idx = r * 32 + (((ci >> 3) ^ swz(r)) << 3) + (ci & 7);
                        pH[idx] = (unsigned short)(p & 0xFFFFu);
                        pL[idx] = (unsigned short)(p >> 16);
                    }
                } else {
                    // packed u32 [B][Tin][CinPad]
                    const unsigned* xp = (const unsigned*)xsrc + (size_t)b * Tin * CinPad + c0;
                    for (int r = tid; r < SPAN; r += 256) {
                        const int t = tbase + r;
                        const bool v = (t >= 0 && t < Tin);
                        const int4* src = v ? (const int4*)(xp + (size_t)t * CinPad) : nullptr;
                        stage_row_packed(src, v, sXh, sXl, r);
                    }
                }
            }
            // stage W (this tap) from raw fp32 w[o][CinReal][TAPS]
            {
                const int orow = tid >> 1, half = tid & 1;
                const int s = swz(orow);
                const float* wp = wraw + ((size_t)(o0 + orow) * CinReal + (c0 + half * 16)) * TAPS + tap;
                unsigned p[16];
#pragma unroll
                for (int j = 0; j < 16; ++j) {
                    const int c = c0 + half * 16 + j;
                    p[j] = (c < CinReal) ? splitpack(wp[(size_t)j * TAPS]) : 0u;
                }
                int4 h0, h1, l0, l1;
                h0.x = (int)((p[0]&0xFFFFu)|(p[1]<<16));   h0.y = (int)((p[2]&0xFFFFu)|(p[3]<<16));
                h0.z = (int)((p[4]&0xFFFFu)|(p[5]<<16));   h0.w = (int)((p[6]&0xFFFFu)|(p[7]<<16));
                h1.x = (int)((p[8]&0xFFFFu)|(p[9]<<16));   h1.y = (int)((p[10]&0xFFFFu)|(p[11]<<16));
                h1.z = (int)((p[12]&0xFFFFu)|(p[13]<<16)); h1.w = (int)((p[14]&0xFFFFu)|(p[15]<<16));
                l0.x = (int)((p[0]>>16)|(p[1]&0xFFFF0000u));   l0.y = (int)((p[2]>>16)|(p[3]&0xFFFF0000u));
                l0.z = (int)((p[4]>>16)|(p[5]&0xFFFF0000u));   l0.w = (int)((p[6]>>16)|(p[7]&0xFFFF0000u));
                l1.x = (int)((p[8]>>16)|(p[9]&0xFFFF0000u));   l1.y = (int)((p[10]>>16)|(p[11]&0xFFFF0000u));
                l1.z = (int)((p[12]>>16)|(p[13]&0xFFFF0000u)); l1.w = (int)((p[14]>>16)|(p[15]&0xFFFF0000u));
                sWh[orow][(half*2+0) ^ s] = h0;  sWh[orow][(half*2+1) ^ s] = h1;
                sWl[orow][(half*2+0) ^ s] = l0;  sWl[orow][(half*2+1) ^ s] = l1;
            }
            __syncthreads();

            // B fragments (o rows)
            B128 bh[4], bl[4];
#pragma unroll
            for (int nf = 0; nf < 4; ++nf) {
                const int orow = wn * 64 + nf * 16 + l15;
                const int sl = l4 ^ swz(orow);
                bh[nf].i = sWh[orow][sl];  bl[nf].i = sWl[orow][sl];
            }
            // A fragments + MFMA
#pragma unroll
            for (int mf = 0; mf < MF; ++mf) {
                const int r = (wm * WM + mf * 16 + l15) * S + tap;
                const int sl = l4 ^ swz(r);
                B128 ah, al;
                ah.i = sXh[r][sl];  al.i = sXl[r][sl];
#pragma unroll
                for (int nf = 0; nf < 4; ++nf) {
                    acc[mf][nf] = __builtin_amdgcn_mfma_f32_16x16x32_bf16(ah.b, bh[nf].b, acc[mf][nf], 0, 0, 0);
                    acc[mf][nf] = __builtin_amdgcn_mfma_f32_16x16x32_bf16(ah.b, bl[nf].b, acc[mf][nf], 0, 0, 0);
                    acc[mf][nf] = __builtin_amdgcn_mfma_f32_16x16x32_bf16(al.b, bh[nf].b, acc[mf][nf], 0, 0, 0);
                }
            }
        }
    }

    // epilogue: D row=(l>>4)*4+reg (t), col=l&15 (o)
#pragma unroll
    for (int nf = 0; nf < 4; ++nf) {
        const int o = o0 + wn * 64 + nf * 16 + l15;
        const float bv = bias[o];
#pragma unroll
        for (int mf = 0; mf < MF; ++mf) {
#pragma unroll
            for (int rg = 0; rg < 4; ++rg) {
                const int Rl = wm * WM + mf * 16 + l4 * 4 + rg;
                const size_t idx = (size_t)(R0 + Rl) * Cout + o;
                float v = acc[mf][nf][rg] + bv;
                if constexpr (ADD)  v += unsplit(addsrc[idx]);
                if constexpr (RELU) v = fmaxf(v, 0.f);
                out[idx] = splitpack(v);
            }
        }
    }
}

// ---------------------------------------------------------------------------
// Codebook prep: cbT[j][d] packed bf16x2 from cb[d][j] fp32 (tiled transpose)
// ---------------------------------------------------------------------------
__global__ void prep_cbT(const float* __restrict__ cb, unsigned* __restrict__ cbT)
{
    __shared__ float tile[32][33];
    const int jb = blockIdx.x * 32, db = blockIdx.y * 32;
    const int c = threadIdx.x & 31, r = threadIdx.x >> 5;
    for (int rr = r; rr < 32; rr += 8)
        tile[rr][c] = cb[(size_t)(db + rr) * N_TOK + jb + c];
    __syncthreads();
    for (int rr = r; rr < 32; rr += 8)
        cbT[(size_t)(jb + rr) * CODE_DIM + db + c] = splitpack(tile[c][rr]);
}

__global__ void cnorm_kernel(const float* __restrict__ cb, float* __restrict__ cnorm)
{
    const int j = blockIdx.x * 256 + threadIdx.x;
    float s = 0.f;
#pragma unroll 8
    for (int d = 0; d < CODE_DIM; ++d) {
        const float v = cb[(size_t)d * N_TOK + j];
        s += v * v;
    }
    cnorm[j] = s;
}

// ---------------------------------------------------------------------------
// VQ: argmax_j (2*f.c_j - |c_j|^2) via MFMA. M=8192 rows x N=8192 codes, K=512.
// Block 256 rows x 128 codes; partial winners per 64-code slice -> merge.
// ---------------------------------------------------------------------------
__global__ __launch_bounds__(256, 2)
void vq_mfma(const unsigned* __restrict__ lat, const unsigned* __restrict__ cbT,
             const float* __restrict__ cnorm,
             float* __restrict__ pval, int* __restrict__ pidx)
{
    __shared__ int4 sXh[256][4], sXl[256][4];
    __shared__ int4 sWh[128][4], sWl[128][4];

    const int tid  = threadIdx.x;
    const int lane = tid & 63, wid = tid >> 6;
    const int wm = wid >> 1, wn = wid & 1;
    const int l15 = lane & 15, l4 = lane >> 4;
    const int R0 = blockIdx.x * 256;
    const int o0 = blockIdx.y * 128;

    f32x4 acc[8][4] = {};

    for (int c0 = 0; c0 < CODE_DIM; c0 += 32) {
        __syncthreads();
        stage_row_packed((const int4*)(lat + ((size_t)(R0 + tid) * CODE_DIM + c0)), true, sXh, sXl, tid);
        if (tid < 128)
            stage_row_packed((const int4*)(cbT + ((size_t)(o0 + tid) * CODE_DIM + c0)), true, sWh, sWl, tid);
        __syncthreads();

        B128 bh[4], bl[4];
#pragma unroll
        for (int nf = 0; nf < 4; ++nf) {
            const int orow = wn * 64 + nf * 16 + l15;
            const int sl = l4 ^ swz(orow);
            bh[nf].i = sWh[orow][sl];  bl[nf].i = sWl[orow][sl];
        }
#pragma unroll
        for (int mf = 0; mf < 8; ++mf) {
            const int r = wm * 128 + mf * 16 + l15;
            const int sl = l4 ^ swz(r);
            B128 ah, al;
            ah.i = sXh[r][sl];  al.i = sXl[r][sl];
#pragma unroll
            for (int nf = 0; nf < 4; ++nf) {
                acc[mf][nf] = __builtin_amdgcn_mfma_f32_16x16x32_bf16(ah.b, bh[nf].b, acc[mf][nf], 0, 0, 0);
                acc[mf][nf] = __builtin_amdgcn_mfma_f32_16x16x32_bf16(ah.b, bl[nf].b, acc[mf][nf], 0, 0, 0);
                acc[mf][nf] = __builtin_amdgcn_mfma_f32_16x16x32_bf16(al.b, bh[nf].b, acc[mf][nf], 0, 0, 0);
            }
        }
    }

    // epilogue: per-lane best over nf, shuffle-reduce over the 16 j-lanes
    float cn[4]; int jb[4];
#pragma unroll
    for (int nf = 0; nf < 4; ++nf) {
        jb[nf] = o0 + wn * 64 + nf * 16 + l15;
        cn[nf] = cnorm[jb[nf]];
    }
    const int slice = blockIdx.y * 2 + wn;
#pragma unroll
    for (int mf = 0; mf < 8; ++mf) {
#pragma unroll
        for (int rg = 0; rg < 4; ++rg) {
            float bv = -3.4e38f; int bj = 0;
#pragma unroll
            for (int nf = 0; nf < 4; ++nf) {           // ascending j: strict > keeps first min
                const float v = 2.f * acc[mf][nf][rg] - cn[nf];
                if (v > bv) { bv = v; bj = jb[nf]; }
            }
#pragma unroll
            for (int m = 1; m < 16; m <<= 1) {
                const float ov = __shfl_xor(bv, m, 64);
                const int   oj = __shfl_xor(bj, m, 64);
                if (ov > bv || (ov == bv && oj < bj)) { bv = ov; bj = oj; }
            }
            if (l15 == 0) {
                const int R = R0 + wm * 128 + mf * 16 + l4 * 4 + rg;
                pval[(size_t)slice * N_ROWS + R] = bv;
                pidx[(size_t)slice * N_ROWS + R] = bj;
            }
        }
    }
}

__global__ void vq_merge(const float* __restrict__ pval, const int* __restrict__ pidx,
                         int* __restrict__ out)
{
    const int row = blockIdx.x * 256 + threadIdx.x;
    float bv = pval[row]; int bj = pidx[row];
    for (int s = 1; s < 128; ++s) {                    // slices ascending in j
        const float v = pval[(size_t)s * N_ROWS + row];
        const int   j = pidx[(size_t)s * N_ROWS + row];
        if (v > bv || (v == bv && j < bj)) { bv = v; bj = j; }
    }
    out[row] = bj;
}

// ---------------------------------------------------------------------------
// Launch
// ---------------------------------------------------------------------------
extern "C" void kernel_launch(void* const* d_in, const int* in_sizes, int n_in,
                              void* d_out, int out_size, void* d_ws, size_t ws_size,
                              hipStream_t stream)
{
    const float* x   = (const float*)d_in[0];
    const float* w1  = (const float*)d_in[1];
    const float* b1  = (const float*)d_in[2];
    const float* w2  = (const float*)d_in[3];
    const float* b2  = (const float*)d_in[4];
    const float* rwa = (const float*)d_in[5];
    const float* rba = (const float*)d_in[6];
    const float* rwb = (const float*)d_in[7];
    const float* rbb = (const float*)d_in[8];
    const float* rwc = (const float*)d_in[9];
    const float* rbc = (const float*)d_in[10];
    const float* wf  = (const float*)d_in[11];
    const float* bf  = (const float*)d_in[12];
    const float* cb  = (const float*)d_in[13];

    // ws (u32 units), total 25,165,824 u32 = 100.7 MB:
    //   [0 .. 8.39M)  h1 / r1 ; after wf: cbT (4.19M) + cnorm + pval + pidx
    //   [8.39M..16.78M) h2
    //   [16.78M..25.17M) r2 ; after resblocks: lat (4.19M)
    unsigned* ws  = (unsigned*)d_ws;
    unsigned* h1  = ws;
    unsigned* h2  = ws + 8388608;
    unsigned* r2  = ws + 16777216;
    unsigned* r1  = h1;
    unsigned* lat = r2;
    unsigned* cbT = ws;
    float*    CN  = (float*)(ws + 4194304);
    float*    PV  = (float*)(ws + 4202496);
    int*      PI  = (int*)(ws + 5251072);

    // conv1: [16,80,2048] fp32 -> relu -> h1 packed [16,1024,512]
    conv_mfma<3, 2, 64, true, true, false><<<dim3(128, 4), 256, 0, stream>>>(
        x, w1, b1, nullptr, h1, 96, 80, HID1, T_IN, T1);
    // conv2: -> relu -> h2 packed [16,512,1024]
    conv_mfma<3, 2, 64, false, true, false><<<dim3(64, 8), 256, 0, stream>>>(
        h1, w2, b2, nullptr, h2, HID1, HID1, HID2, T1, T2);
    // 3 resblocks
    for (int i = 0; i < N_RES; ++i) {
        conv_mfma<3, 1, 128, false, true, false><<<dim3(32, 8), 256, 0, stream>>>(
            h2, rwa + (size_t)i * 3145728, rba + (size_t)i * HID2, nullptr, r1,
            HID2, HID2, HID2, T2, T2);
        conv_mfma<3, 1, 128, false, true, false><<<dim3(32, 8), 256, 0, stream>>>(
            r1, rwb + (size_t)i * 3145728, rbb + (size_t)i * HID2, nullptr, r2,
            HID2, HID2, HID2, T2, T2);
        conv_mfma<1, 1, 128, false, false, true><<<dim3(32, 8), 256, 0, stream>>>(
            r2, rwc + (size_t)i * 1048576, rbc + (size_t)i * HID2, h2, h2,
            HID2, HID2, HID2, T2, T2);
    }
    // final 1x1 -> lat packed [16,512,512]
    conv_mfma<1, 1, 128, false, false, false><<<dim3(32, 4), 256, 0, stream>>>(
        h2, wf, bf, nullptr, lat, HID2, HID2, CODE_DIM, T2, T2);

    // VQ argmin
    prep_cbT<<<dim3(N_TOK / 32, CODE_DIM / 32), 256, 0, stream>>>(cb, cbT);
    cnorm_kernel<<<N_TOK / 256, 256, 0, stream>>>(cb, CN);
    vq_mfma<<<dim3(N_ROWS / 256, N_TOK / 128), 256, 0, stream>>>(lat, cbT, CN, PV, PI);
    vq_merge<<<N_ROWS / 256, 256, 0, stream>>>(PV, PI, (int*)d_out);
}

// Round 4
// 2176.121 us; speedup vs baseline: 3.3078x; 2.0251x over previous
//
#include <hip/hip_runtime.h>
#include <cstdint>

// ---------------------------------------------------------------------------
#define BATCH   16
#define T_IN    2048
#define HID1    512
#define HID2    1024
#define T1      1024
#define T2      512
#define CODE_DIM 512
#define N_TOK   8192
#define N_RES   3
#define N_ROWS  (BATCH * T2)

typedef short bf16x8 __attribute__((ext_vector_type(8)));
typedef float f32x4  __attribute__((ext_vector_type(4)));
typedef unsigned short u16;

union B128 { int4 i; bf16x8 b; };

// bf16x2 split: u32 = hi_bits | (lo_bits << 16); v ~= bf16(hi) + bf16(lo)
__device__ __forceinline__ unsigned splitpack(float v) {
    unsigned r  = __float_as_uint(v);
    unsigned hi = (r + 0x7FFFu + ((r >> 16) & 1u)) >> 16;
    float    res = v - __uint_as_float(hi << 16);
    unsigned rl = __float_as_uint(res);
    unsigned lo = (rl + 0x7FFFu + ((rl >> 16) & 1u)) >> 16;
    return hi | (lo << 16);
}
__device__ __forceinline__ float bf2f(u16 b) { return __uint_as_float(((unsigned)b) << 16); }
__device__ __forceinline__ int swz(int row) { return (row ^ (row >> 2)) & 3; }

// ---------------------------------------------------------------------------
// MFMA implicit-GEMM conv1d over plane-split activations (see round notes).
// Block: BM=2*WR rows x BN=128 cols, 4 waves (2x2), wave tile WR x 64.
// ---------------------------------------------------------------------------
template<int TAPS, int S, int WR, bool WPRE, bool RELU, bool ADD>
__global__ __launch_bounds__(256, 2)
void conv_mfma(const u16* __restrict__ xH, const u16* __restrict__ xL,
               const float* __restrict__ wraw,
               const u16* __restrict__ wHp, const u16* __restrict__ wLp,
               const float* __restrict__ bias,
               const u16* __restrict__ addH, const u16* __restrict__ addL,
               u16* __restrict__ oH, u16* __restrict__ oL,
               int Cin, int Cout, int Tin, int Tout, int ntc)
{
    constexpr int BM = WR * 2, BN = 128;
    constexpr int PAD  = (TAPS == 3) ? 1 : 0;
    constexpr int SPAN = BM * S + TAPS - S;
    constexpr int MF   = WR / 16;

    __shared__ int4 sXh[SPAN][4], sXl[SPAN][4];
    __shared__ int4 sWh[BN][4],  sWl[BN][4];

    const int tid  = threadIdx.x;
    const int lane = tid & 63, wid = tid >> 6;
    const int wm = wid >> 1, wn = wid & 1;
    const int l15 = lane & 15, l4 = lane >> 4;

    const int bid = blockIdx.x;
    const int nt = bid % ntc, mt = bid / ntc;   // same-nt blocks on same XCD (rr heuristic)
    const int R0 = mt * BM, o0 = nt * BN;
    const int b  = R0 / Tout, t0 = R0 % Tout;
    const int tbase = t0 * S - PAD;

    f32x4 acc[MF][4] = {};

    const u16* bxH = xH + (size_t)b * Tin * Cin;
    const u16* bxL = xL + (size_t)b * Tin * Cin;

    for (int c0 = 0; c0 < Cin; c0 += 32) {
        for (int tap = 0; tap < TAPS; ++tap) {
            __syncthreads();
            if (tap == 0) {
                for (int r = tid; r < SPAN; r += 256) {
                    const int t = tbase + r;
                    const int s = swz(r);
                    if (t >= 0 && t < Tin) {
                        const int4* pH = (const int4*)(bxH + (size_t)t * Cin + c0);
                        const int4* pL = (const int4*)(bxL + (size_t)t * Cin + c0);
#pragma unroll
                        for (int j = 0; j < 4; ++j) sXh[r][j ^ s] = pH[j];
#pragma unroll
                        for (int j = 0; j < 4; ++j) sXl[r][j ^ s] = pL[j];
                    } else {
                        const int4 z = {0, 0, 0, 0};
#pragma unroll
                        for (int j = 0; j < 4; ++j) { sXh[r][j] = z; sXl[r][j] = z; }
                    }
                }
            }
            if constexpr (WPRE) {
                const int row = tid & 127, half = tid >> 7;
                const int s = swz(row);
                const size_t base = ((size_t)tap * Cout + (o0 + row)) * Cin + c0 + half * 16;
                const int4* pH = (const int4*)(wHp + base);
                const int4* pL = (const int4*)(wLp + base);
                sWh[row][(half * 2 + 0) ^ s] = pH[0];
                sWh[row][(half * 2 + 1) ^ s] = pH[1];
                sWl[row][(half * 2 + 0) ^ s] = pL[0];
                sWl[row][(half * 2 + 1) ^ s] = pL[1];
            } else {
                const int row = tid >> 1, half = tid & 1;
                const int s = swz(row);
                const float* wp = wraw + ((size_t)(o0 + row) * Cin + (c0 + half * 16)) * TAPS + tap;
                unsigned p[16];
#pragma unroll
                for (int j = 0; j < 16; ++j) p[j] = splitpack(wp[(size_t)j * TAPS]);
                int4 h0, h1, l0, l1;
                h0.x = (int)((p[0]&0xFFFFu)|(p[1]<<16));   h0.y = (int)((p[2]&0xFFFFu)|(p[3]<<16));
                h0.z = (int)((p[4]&0xFFFFu)|(p[5]<<16));   h0.w = (int)((p[6]&0xFFFFu)|(p[7]<<16));
                h1.x = (int)((p[8]&0xFFFFu)|(p[9]<<16));   h1.y = (int)((p[10]&0xFFFFu)|(p[11]<<16));
                h1.z = (int)((p[12]&0xFFFFu)|(p[13]<<16)); h1.w = (int)((p[14]&0xFFFFu)|(p[15]<<16));
                l0.x = (int)((p[0]>>16)|(p[1]&0xFFFF0000u));   l0.y = (int)((p[2]>>16)|(p[3]&0xFFFF0000u));
                l0.z = (int)((p[4]>>16)|(p[5]&0xFFFF0000u));   l0.w = (int)((p[6]>>16)|(p[7]&0xFFFF0000u));
                l1.x = (int)((p[8]>>16)|(p[9]&0xFFFF0000u));   l1.y = (int)((p[10]>>16)|(p[11]&0xFFFF0000u));
                l1.z = (int)((p[12]>>16)|(p[13]&0xFFFF0000u)); l1.w = (int)((p[14]>>16)|(p[15]&0xFFFF0000u));
                sWh[row][(half * 2 + 0) ^ s] = h0;  sWh[row][(half * 2 + 1) ^ s] = h1;
                sWl[row][(half * 2 + 0) ^ s] = l0;  sWl[row][(half * 2 + 1) ^ s] = l1;
            }
            __syncthreads();

            B128 bh[4], bl[4];
#pragma unroll
            for (int nf = 0; nf < 4; ++nf) {
                const int orow = wn * 64 + nf * 16 + l15;
                const int sl = l4 ^ swz(orow);
                bh[nf].i = sWh[orow][sl];  bl[nf].i = sWl[orow][sl];
            }
#pragma unroll
            for (int mf = 0; mf < MF; ++mf) {
                const int r = (wm * WR + mf * 16 + l15) * S + tap;
                const int sl = l4 ^ swz(r);
                B128 ah, al;
                ah.i = sXh[r][sl];  al.i = sXl[r][sl];
#pragma unroll
                for (int nf = 0; nf < 4; ++nf) {
                    acc[mf][nf] = __builtin_amdgcn_mfma_f32_16x16x32_bf16(ah.b, bh[nf].b, acc[mf][nf], 0, 0, 0);
                    acc[mf][nf] = __builtin_amdgcn_mfma_f32_16x16x32_bf16(ah.b, bl[nf].b, acc[mf][nf], 0, 0, 0);
                    acc[mf][nf] = __builtin_amdgcn_mfma_f32_16x16x32_bf16(al.b, bh[nf].b, acc[mf][nf], 0, 0, 0);
                }
            }
        }
    }

#pragma unroll
    for (int nf = 0; nf < 4; ++nf) {
        const int o = o0 + wn * 64 + nf * 16 + l15;
        const float bv = bias[o];
#pragma unroll
        for (int mf = 0; mf < MF; ++mf) {
#pragma unroll
            for (int rg = 0; rg < 4; ++rg) {
                const int Rl = wm * WR + mf * 16 + l4 * 4 + rg;
                const size_t idx = (size_t)(R0 + Rl) * Cout + o;
                float v = acc[mf][nf][rg] + bv;
                if constexpr (ADD)  v += bf2f(addH[idx]) + bf2f(addL[idx]);
                if constexpr (RELU) v = fmaxf(v, 0.f);
                const unsigned p = splitpack(v);
                oH[idx] = (u16)(p & 0xFFFFu);
                oL[idx] = (u16)(p >> 16);
            }
        }
    }
}

// ---------------------------------------------------------------------------
// Prep kernels
// ---------------------------------------------------------------------------
__global__ void prep_x(const float* __restrict__ x, u16* __restrict__ xH, u16* __restrict__ xL)
{
    const int id = blockIdx.x * 256 + threadIdx.x;     // (b,t)
    const int b = id >> 11, t = id & 2047;
    const float* src = x + (size_t)b * 80 * 2048 + t;
    u16* dH = xH + (size_t)id * 96;
    u16* dL = xL + (size_t)id * 96;
    for (int c = 0; c < 96; ++c) {
        const float v = (c < 80) ? src[(size_t)c * 2048] : 0.f;
        const unsigned p = splitpack(v);
        dH[c] = (u16)(p & 0xFFFFu);
        dL[c] = (u16)(p >> 16);
    }
}

// w fp32 [O][CinR][TAPS] -> planes [TAPS][O][CinP] (c >= CinR zero-padded)
__global__ void prep_w(const float* __restrict__ w, u16* __restrict__ wH, u16* __restrict__ wL,
                       int O, int CinR, int CinP, int TAPS)
{
    const int id = blockIdx.x * 256 + threadIdx.x;     // (o, c) over CinP
    if (id >= O * CinP) return;
    const int o = id / CinP, c = id % CinP;
    for (int t = 0; t < TAPS; ++t) {
        const float v = (c < CinR) ? w[((size_t)o * CinR + c) * TAPS + t] : 0.f;
        const unsigned p = splitpack(v);
        const size_t dst = ((size_t)t * O + o) * CinP + c;
        wH[dst] = (u16)(p & 0xFFFFu);
        wL[dst] = (u16)(p >> 16);
    }
}

__global__ void prep_cb(const float* __restrict__ cb, u16* __restrict__ cH, u16* __restrict__ cL)
{
    __shared__ float tile[32][33];
    const int jb = blockIdx.x * 32, db = blockIdx.y * 32;
    const int c = threadIdx.x & 31, r = threadIdx.x >> 5;
    for (int rr = r; rr < 32; rr += 8)
        tile[rr][c] = cb[(size_t)(db + rr) * N_TOK + jb + c];
    __syncthreads();
    for (int rr = r; rr < 32; rr += 8) {
        const unsigned p = splitpack(tile[c][rr]);
        const size_t dst = (size_t)(jb + rr) * CODE_DIM + db + c;
        cH[dst] = (u16)(p & 0xFFFFu);
        cL[dst] = (u16)(p >> 16);
    }
}

__global__ void cnorm_kernel(const float* __restrict__ cb, float* __restrict__ cnorm)
{
    const int j = blockIdx.x * 256 + threadIdx.x;
    float s = 0.f;
#pragma unroll 8
    for (int d = 0; d < CODE_DIM; ++d) {
        const float v = cb[(size_t)d * N_TOK + j];
        s += v * v;
    }
    cnorm[j] = s;
}

// ---------------------------------------------------------------------------
// VQ: argmax_j (2*f.c_j - |c_j|^2). Block 256 rows x 128 codes, plane staging.
// ---------------------------------------------------------------------------
__global__ __launch_bounds__(256, 2)
void vq_mfma(const u16* __restrict__ latH, const u16* __restrict__ latL,
             const u16* __restrict__ cbH, const u16* __restrict__ cbL,
             const float* __restrict__ cnorm,
             float* __restrict__ pval, int* __restrict__ pidx)
{
    __shared__ int4 sXh[256][4], sXl[256][4];
    __shared__ int4 sWh[128][4], sWl[128][4];

    const int tid  = threadIdx.x;
    const int lane = tid & 63, wid = tid >> 6;
    const int wm = wid >> 1, wn = wid & 1;
    const int l15 = lane & 15, l4 = lane >> 4;
    const int R0 = blockIdx.x * 256;
    const int o0 = blockIdx.y * 128;

    f32x4 acc[8][4] = {};

    for (int c0 = 0; c0 < CODE_DIM; c0 += 32) {
        __syncthreads();
        {
            const int s = swz(tid);
            const int4* pH = (const int4*)(latH + (size_t)(R0 + tid) * CODE_DIM + c0);
            const int4* pL = (const int4*)(latL + (size_t)(R0 + tid) * CODE_DIM + c0);
#pragma unroll
            for (int j = 0; j < 4; ++j) sXh[tid][j ^ s] = pH[j];
#pragma unroll
            for (int j = 0; j < 4; ++j) sXl[tid][j ^ s] = pL[j];
        }
        {
            const int row = tid & 127, half = tid >> 7;
            const int s = swz(row);
            const size_t base = (size_t)(o0 + row) * CODE_DIM + c0 + half * 16;
            const int4* pH = (const int4*)(cbH + base);
            const int4* pL = (const int4*)(cbL + base);
            sWh[row][(half * 2 + 0) ^ s] = pH[0];
            sWh[row][(half * 2 + 1) ^ s] = pH[1];
            sWl[row][(half * 2 + 0) ^ s] = pL[0];
            sWl[row][(half * 2 + 1) ^ s] = pL[1];
        }
        __syncthreads();

        B128 bh[4], bl[4];
#pragma unroll
        for (int nf = 0; nf < 4; ++nf) {
            const int orow = wn * 64 + nf * 16 + l15;
            const int sl = l4 ^ swz(orow);
            bh[nf].i = sWh[orow][sl];  bl[nf].i = sWl[orow][sl];
        }
#pragma unroll
        for (int mf = 0; mf < 8; ++mf) {
            const int r = wm * 128 + mf * 16 + l15;
            const int sl = l4 ^ swz(r);
            B128 ah, al;
            ah.i = sXh[r][sl];  al.i = sXl[r][sl];
#pragma unroll
            for (int nf = 0; nf < 4; ++nf) {
                acc[mf][nf] = __builtin_amdgcn_mfma_f32_16x16x32_bf16(ah.b, bh[nf].b, acc[mf][nf], 0, 0, 0);
                acc[mf][nf] = __builtin_amdgcn_mfma_f32_16x16x32_bf16(ah.b, bl[nf].b, acc[mf][nf], 0, 0, 0);
                acc[mf][nf] = __builtin_amdgcn_mfma_f32_16x16x32_bf16(al.b, bh[nf].b, acc[mf][nf], 0, 0, 0);
            }
        }
    }

    float cn[4]; int jb[4];
#pragma unroll
    for (int nf = 0; nf < 4; ++nf) {
        jb[nf] = o0 + wn * 64 + nf * 16 + l15;
        cn[nf] = cnorm[jb[nf]];
    }
    const int slice = blockIdx.y * 2 + wn;
#pragma unroll
    for (int mf = 0; mf < 8; ++mf) {
#pragma unroll
        for (int rg = 0; rg < 4; ++rg) {
            float bv = -3.4e38f; int bj = 0;
#pragma unroll
            for (int nf = 0; nf < 4; ++nf) {      // ascending j: strict > keeps first min
                const float v = 2.f * acc[mf][nf][rg] - cn[nf];
                if (v > bv) { bv = v; bj = jb[nf]; }
            }
#pragma unroll
            for (int m = 1; m < 16; m <<= 1) {
                const float ov = __shfl_xor(bv, m, 64);
                const int   oj = __shfl_xor(bj, m, 64);
                if (ov > bv || (ov == bv && oj < bj)) { bv = ov; bj = oj; }
            }
            if (l15 == 0) {
                const int R = R0 + wm * 128 + mf * 16 + l4 * 4 + rg;
                pval[(size_t)slice * N_ROWS + R] = bv;
                pidx[(size_t)slice * N_ROWS + R] = bj;
            }
        }
    }
}

__global__ void vq_merge(const float* __restrict__ pval, const int* __restrict__ pidx,
                         int* __restrict__ out)
{
    const int row = blockIdx.x * 256 + threadIdx.x;
    float bv = pval[row]; int bj = pidx[row];
    for (int s = 1; s < 128; ++s) {
        const float v = pval[(size_t)s * N_ROWS + row];
        const int   j = pidx[(size_t)s * N_ROWS + row];
        if (v > bv || (v == bv && j < bj)) { bv = v; bj = j; }
    }
    out[row] = bj;
}

// ---------------------------------------------------------------------------
// Launch
// ---------------------------------------------------------------------------
extern "C" void kernel_launch(void* const* d_in, const int* in_sizes, int n_in,
                              void* d_out, int out_size, void* d_ws, size_t ws_size,
                              hipStream_t stream)
{
    const float* x   = (const float*)d_in[0];
    const float* w1  = (const float*)d_in[1];
    const float* b1  = (const float*)d_in[2];
    const float* w2  = (const float*)d_in[3];
    const float* b2  = (const float*)d_in[4];
    const float* rwa = (const float*)d_in[5];
    const float* rba = (const float*)d_in[6];
    const float* rwb = (const float*)d_in[7];
    const float* rbb = (const float*)d_in[8];
    const float* rwc = (const float*)d_in[9];
    const float* rbc = (const float*)d_in[10];
    const float* wf  = (const float*)d_in[11];
    const float* bf  = (const float*)d_in[12];
    const float* cb  = (const float*)d_in[13];

    char* W = (char*)d_ws;
    // byte layout (base footprint = 100,663,296 B, proven safe round 3):
    //   R_h1 @0        : h1 planes -> r1 planes -> lat planes
    //   R_h2 @33.55M   : h2 planes
    //   R_r2 @67.11M   : early xP+w1P+w2P -> r2 planes -> cbT+CN+PV+PI
    //   R_wrot @100.66M (+31.46M, only if ws_size allows): rwaP,rwbP,rwcP,wfP
    u16* h1H = (u16*)(W + 0);          u16* h1L = (u16*)(W + 16777216);
    u16* h2H = (u16*)(W + 33554432);   u16* h2L = (u16*)(W + 50331648);
    u16* r2H = (u16*)(W + 67108864);   u16* r2L = (u16*)(W + 83886080);
    u16* r1H = h1H;                    u16* r1L = h1L;
    u16* latH = h1H;                   u16* latL = h1L;
    u16* xPH  = (u16*)(W + 67108864);  u16* xPL  = (u16*)(W + 73400320);
    u16* w1PH = (u16*)(W + 79691776);  u16* w1PL = (u16*)(W + 79986688);
    u16* w2PH = (u16*)(W + 80281600);  u16* w2PL = (u16*)(W + 83427328);
    u16* cbTH = (u16*)(W + 67108864);  u16* cbTL = (u16*)(W + 75497472);
    float* CN = (float*)(W + 83886080);
    float* PV = (float*)(W + 83918848);
    int*   PI = (int*)(W + 88113152);
    const bool WPRE = ws_size >= (size_t)132120576;
    u16* raPH = (u16*)(W + 100663296); u16* raPL = (u16*)(W + 106954752);
    u16* rbPH = (u16*)(W + 113246208); u16* rbPL = (u16*)(W + 119537664);
    u16* rcPH = (u16*)(W + 125829120); u16* rcPL = (u16*)(W + 127926272);
    u16* wfPH = (u16*)(W + 130023424); u16* wfPL = (u16*)(W + 131072000);

    prep_x<<<BATCH * T_IN / 256, 256, 0, stream>>>(x, xPH, xPL);
    prep_w<<<(HID1 * 96 + 255) / 256, 256, 0, stream>>>(w1, w1PH, w1PL, HID1, 80, 96, 3);
    prep_w<<<(HID2 * HID1 + 255) / 256, 256, 0, stream>>>(w2, w2PH, w2PL, HID2, HID1, HID1, 3);

    // conv1: xP -> relu -> h1   [M=16384, N=512]
    conv_mfma<3, 2, 64, true, true, false><<<512, 256, 0, stream>>>(
        xPH, xPL, nullptr, w1PH, w1PL, b1, nullptr, nullptr, h1H, h1L,
        96, HID1, T_IN, T1, 4);
    // conv2: h1 -> relu -> h2   [M=8192, N=1024]
    conv_mfma<3, 2, 64, true, true, false><<<512, 256, 0, stream>>>(
        h1H, h1L, nullptr, w2PH, w2PL, b2, nullptr, nullptr, h2H, h2L,
        HID1, HID2, T1, T2, 8);

    for (int i = 0; i < N_RES; ++i) {
        const float* wa = rwa + (size_t)i * HID2 * HID2 * 3;
        const float* wb = rwb + (size_t)i * HID2 * HID2 * 3;
        const float* wc = rwc + (size_t)i * HID2 * HID2;
        if (WPRE) {
            prep_w<<<(HID2 * HID2 + 255) / 256, 256, 0, stream>>>(wa, raPH, raPL, HID2, HID2, HID2, 3);
            prep_w<<<(HID2 * HID2 + 255) / 256, 256, 0, stream>>>(wb, rbPH, rbPL, HID2, HID2, HID2, 3);
            prep_w<<<(HID2 * HID2 + 255) / 256, 256, 0, stream>>>(wc, rcPH, rcPL, HID2, HID2, HID2, 1);
            conv_mfma<3, 1, 64, true, true, false><<<512, 256, 0, stream>>>(
                h2H, h2L, nullptr, raPH, raPL, rba + (size_t)i * HID2, nullptr, nullptr,
                r1H, r1L, HID2, HID2, T2, T2, 8);
            conv_mfma<3, 1, 64, true, true, false><<<512, 256, 0, stream>>>(
                r1H, r1L, nullptr, rbPH, rbPL, rbb + (size_t)i * HID2, nullptr, nullptr,
                r2H, r2L, HID2, HID2, T2, T2, 8);
            conv_mfma<1, 1, 64, true, false, true><<<512, 256, 0, stream>>>(
                r2H, r2L, nullptr, rcPH, rcPL, rbc + (size_t)i * HID2, h2H, h2L,
                h2H, h2L, HID2, HID2, T2, T2, 8);
        } else {
            conv_mfma<3, 1, 64, false, true, false><<<512, 256, 0, stream>>>(
                h2H, h2L, wa, nullptr, nullptr, rba + (size_t)i * HID2, nullptr, nullptr,
                r1H, r1L, HID2, HID2, T2, T2, 8);
            conv_mfma<3, 1, 64, false, true, false><<<512, 256, 0, stream>>>(
                r1H, r1L, wb, nullptr, nullptr, rbb + (size_t)i * HID2, nullptr, nullptr,
                r2H, r2L, HID2, HID2, T2, T2, 8);
            conv_mfma<1, 1, 64, false, false, true><<<512, 256, 0, stream>>>(
                r2H, r2L, wc, nullptr, nullptr, rbc + (size_t)i * HID2, h2H, h2L,
                h2H, h2L, HID2, HID2, T2, T2, 8);
        }
    }

    // final 1x1: h2 -> lat  [M=8192, N=512], BM=64 -> grid 512
    if (WPRE) {
        prep_w<<<(CODE_DIM * HID2 + 255) / 256, 256, 0, stream>>>(wf, wfPH, wfPL, CODE_DIM, HID2, HID2, 1);
        conv_mfma<1, 1, 32, true, false, false><<<512, 256, 0, stream>>>(
            h2H, h2L, nullptr, wfPH, wfPL, bf, nullptr, nullptr, latH, latL,
            HID2, CODE_DIM, T2, T2, 4);
    } else {
        conv_mfma<1, 1, 32, false, false, false><<<512, 256, 0, stream>>>(
            h2H, h2L, wf, nullptr, nullptr, bf, nullptr, nullptr, latH, latL,
            HID2, CODE_DIM, T2, T2, 4);
    }

    // VQ argmin
    prep_cb<<<dim3(N_TOK / 32, CODE_DIM / 32), 256, 0, stream>>>(cb, cbTH, cbTL);
    cnorm_kernel<<<N_TOK / 256, 256, 0, stream>>>(cb, CN);
    vq_mfma<<<dim3(N_ROWS / 256, N_TOK / 128), 256, 0, stream>>>(latH, latL, cbTH, cbTL, CN, PV, PI);
    vq_merge<<<N_ROWS / 256, 256, 0, stream>>>(PV, PI, (int*)d_out);
}